// Round 1
// baseline (679.160 us; speedup 1.0000x reference)
//
#include <hip/hip_runtime.h>
#include <math.h>

#define N_NODES 50000
#define SEQ_LEN 32
#define EMB_DIM 128
#define IN_FEATS 256
#define N_HIDDEN 256
#define N_CLASSES 40
#define N_EDGES 800000

constexpr int SCAN_CHUNK = 512;
constexpr int N_CHUNKS = (N_NODES + SCAN_CHUNK - 1) / SCAN_CHUNK; // 98

// ---------------- degree / norms ----------------
__global__ __launch_bounds__(256) void k_degree(const int* __restrict__ src,
                                                const int* __restrict__ dst,
                                                int* __restrict__ deg_out,
                                                int* __restrict__ deg_in) {
  int e = blockIdx.x * 256 + threadIdx.x;
  if (e < N_EDGES) {
    atomicAdd(&deg_out[src[e]], 1);
    atomicAdd(&deg_in[dst[e]], 1);
  }
}

__global__ __launch_bounds__(256) void k_norm(const int* __restrict__ deg_out,
                                              const int* __restrict__ deg_in,
                                              float* __restrict__ norm_s,
                                              float* __restrict__ norm_d) {
  int i = blockIdx.x * 256 + threadIdx.x;
  if (i < N_NODES) {
    norm_s[i] = 1.0f / sqrtf((float)max(deg_out[i], 1));
    norm_d[i] = 1.0f / sqrtf((float)max(deg_in[i], 1));
  }
}

// ---------------- scan (offsets from deg_in) ----------------
__global__ __launch_bounds__(SCAN_CHUNK) void k_chunksum(const int* __restrict__ deg,
                                                         int* __restrict__ sums) {
  __shared__ int s[SCAN_CHUNK];
  int i = blockIdx.x * SCAN_CHUNK + threadIdx.x;
  s[threadIdx.x] = (i < N_NODES) ? deg[i] : 0;
  __syncthreads();
  for (int st = SCAN_CHUNK / 2; st > 0; st >>= 1) {
    if (threadIdx.x < st) s[threadIdx.x] += s[threadIdx.x + st];
    __syncthreads();
  }
  if (threadIdx.x == 0) sums[blockIdx.x] = s[0];
}

__global__ void k_topscan(int* __restrict__ sums) {
  if (threadIdx.x == 0 && blockIdx.x == 0) {
    int run = 0;
    for (int b = 0; b < N_CHUNKS; ++b) { int t = sums[b]; sums[b] = run; run += t; }
  }
}

__global__ __launch_bounds__(SCAN_CHUNK) void k_chunkscan(const int* __restrict__ deg,
                                                          const int* __restrict__ chunkOff,
                                                          int* __restrict__ offs) {
  __shared__ int s[SCAN_CHUNK];
  int i = blockIdx.x * SCAN_CHUNK + threadIdx.x;
  int v = (i < N_NODES) ? deg[i] : 0;
  s[threadIdx.x] = v;
  __syncthreads();
  for (int st = 1; st < SCAN_CHUNK; st <<= 1) {
    int t = (threadIdx.x >= st) ? s[threadIdx.x - st] : 0;
    __syncthreads();
    s[threadIdx.x] += t;
    __syncthreads();
  }
  if (i < N_NODES) offs[i + 1] = chunkOff[blockIdx.x] + s[threadIdx.x];
  if (i == 0) offs[0] = 0;
}

__global__ __launch_bounds__(256) void k_csr_fill(const int* __restrict__ src,
                                                  const int* __restrict__ dst,
                                                  const int* __restrict__ offs,
                                                  int* __restrict__ cursor,
                                                  int* __restrict__ csr_src) {
  int e = blockIdx.x * 256 + threadIdx.x;
  if (e < N_EDGES) {
    int d = dst[e];
    int p = atomicAdd(&cursor[d], 1);
    csr_src[offs[d] + p] = src[e];
  }
}

// ---------------- embedding + pooling ----------------
__global__ __launch_bounds__(128) void k_embed(const int* __restrict__ feats,
                                               const float* __restrict__ emb,
                                               float* __restrict__ h) {
  int node = blockIdx.x;
  int tid = threadIdx.x; // 128 = EMB_DIM
  __shared__ int s_tok[SEQ_LEN];
  __shared__ float s_inv;
  if (tid < SEQ_LEN) s_tok[tid] = feats[(size_t)node * SEQ_LEN + tid];
  __syncthreads();
  if (tid == 0) {
    int c = 0;
    #pragma unroll
    for (int t = 0; t < SEQ_LEN; ++t) c += (s_tok[t] != 0);
    s_inv = 1.0f / (float)max(c, 1);
  }
  __syncthreads();
  float sum = 0.f, mx = -INFINITY;
  #pragma unroll
  for (int t = 0; t < SEQ_LEN; ++t) {
    int tok = s_tok[t];
    float v = (tok != 0) ? emb[(size_t)tok * EMB_DIM + tid] : 0.0f;
    sum += v;
    mx = fmaxf(mx, v);
  }
  h[(size_t)node * IN_FEATS + tid] = sum * s_inv;
  h[(size_t)node * IN_FEATS + EMB_DIM + tid] = mx;
}

// ---------------- GEMM1: hw_scaled = (h @ W1) * norm_s ----------------
// 16 rows x 256 cols per block, 256 threads, 4x4 register tile per thread.
__global__ __launch_bounds__(256) void k_gemm1(const float* __restrict__ h,
                                               const float* __restrict__ W,
                                               const float* __restrict__ norm_s,
                                               float* __restrict__ out) {
  __shared__ float s_h[16][IN_FEATS]; // 16KB, row-major
  int tid = threadIdx.x;
  int r0 = blockIdx.x * 16;
  const float4* hv = (const float4*)(h + (size_t)r0 * IN_FEATS);
  float4* sv = (float4*)s_h;
  #pragma unroll
  for (int idx = tid; idx < 16 * (IN_FEATS / 4); idx += 256) sv[idx] = hv[idx];
  __syncthreads();

  int tx = tid & 63;   // col group: cols 4*tx .. 4*tx+3
  int ty = tid >> 6;   // row group: rows 4*ty .. 4*ty+3 (wave-uniform)
  float acc[4][4] = {{0.f}};
  for (int k = 0; k < IN_FEATS; k += 4) {
    float4 a[4];
    #pragma unroll
    for (int r = 0; r < 4; ++r) a[r] = *(const float4*)&s_h[4 * ty + r][k];
    #pragma unroll
    for (int kk = 0; kk < 4; ++kk) {
      float4 w = *(const float4*)(W + (size_t)(k + kk) * N_HIDDEN + 4 * tx);
      #pragma unroll
      for (int r = 0; r < 4; ++r) {
        float av = (kk == 0) ? a[r].x : (kk == 1) ? a[r].y : (kk == 2) ? a[r].z : a[r].w;
        acc[r][0] += av * w.x;
        acc[r][1] += av * w.y;
        acc[r][2] += av * w.z;
        acc[r][3] += av * w.w;
      }
    }
  }
  #pragma unroll
  for (int r = 0; r < 4; ++r) {
    int row = r0 + 4 * ty + r;
    float ns = norm_s[row];
    float4 o = make_float4(acc[r][0] * ns, acc[r][1] * ns, acc[r][2] * ns, acc[r][3] * ns);
    *(float4*)(out + (size_t)row * N_HIDDEN + 4 * tx) = o;
  }
}

// ---------------- aggregation layer 1 (relu + bias + norm_d) ----------------
__global__ __launch_bounds__(256) void k_agg1(const float* __restrict__ msg,
                                              const int* __restrict__ offs,
                                              const int* __restrict__ csr_src,
                                              const float* __restrict__ norm_d,
                                              const float* __restrict__ b1,
                                              float* __restrict__ out) {
  int node = blockIdx.x;
  int tid = threadIdx.x; // 256 = N_HIDDEN
  int beg = offs[node], end = offs[node + 1];
  float acc = 0.f;
  for (int e = beg; e < end; ++e) {
    int s = csr_src[e];
    acc += msg[(size_t)s * N_HIDDEN + tid];
  }
  out[(size_t)node * N_HIDDEN + tid] = fmaxf(acc * norm_d[node] + b1[tid], 0.f);
}

// ---------------- GEMM2: hw2_scaled = (h2 @ W2) * norm_s ----------------
// 32 rows per block, 256 threads, 5 outputs per thread (32*40=1280).
__global__ __launch_bounds__(256) void k_gemm2(const float* __restrict__ h2,
                                               const float* __restrict__ W2,
                                               const float* __restrict__ norm_s,
                                               float* __restrict__ out) {
  __shared__ float s_h[32][N_HIDDEN + 1]; // +1 pad: avoid bank conflicts on column reads
  int tid = threadIdx.x;
  int r0 = blockIdx.x * 32;
  for (int idx = tid; idx < 32 * N_HIDDEN; idx += 256) {
    int r = idx >> 8, k = idx & 255;
    int row = r0 + r;
    s_h[r][k] = (row < N_NODES) ? h2[(size_t)row * N_HIDDEN + k] : 0.f;
  }
  __syncthreads();

  float acc[5] = {0.f, 0.f, 0.f, 0.f, 0.f};
  int rr[5], jj[5];
  #pragma unroll
  for (int i = 0; i < 5; ++i) {
    int o = tid + i * 256;
    rr[i] = o & 31;
    jj[i] = o >> 5;
  }
  for (int k = 0; k < N_HIDDEN; ++k) {
    #pragma unroll
    for (int i = 0; i < 5; ++i) acc[i] += s_h[rr[i]][k] * W2[(size_t)k * N_CLASSES + jj[i]];
  }
  #pragma unroll
  for (int i = 0; i < 5; ++i) {
    int row = r0 + rr[i];
    if (row < N_NODES) out[(size_t)row * N_CLASSES + jj[i]] = acc[i] * norm_s[row];
  }
}

// ---------------- aggregation layer 2 (bias + norm_d) -> d_out ----------------
__global__ __launch_bounds__(256) void k_agg2(const float* __restrict__ msg,
                                              const int* __restrict__ offs,
                                              const int* __restrict__ csr_src,
                                              const float* __restrict__ norm_d,
                                              const float* __restrict__ b2,
                                              float* __restrict__ out) {
  int tid = threadIdx.x;
  int lane = tid & 63, sub = tid >> 6;
  int node = blockIdx.x * 4 + sub;
  if (node >= N_NODES) return;
  int beg = offs[node], end = offs[node + 1];
  if (lane < N_CLASSES) {
    float acc = 0.f;
    for (int e = beg; e < end; ++e) {
      int s = csr_src[e];
      acc += msg[(size_t)s * N_CLASSES + lane];
    }
    out[(size_t)node * N_CLASSES + lane] = acc * norm_d[node] + b2[lane];
  }
}

extern "C" void kernel_launch(void* const* d_in, const int* in_sizes, int n_in,
                              void* d_out, int out_size, void* d_ws, size_t ws_size,
                              hipStream_t stream) {
  const int*   feats = (const int*)d_in[0];
  const int*   src   = (const int*)d_in[1];
  const int*   dst   = (const int*)d_in[2];
  const float* emb   = (const float*)d_in[3];
  const float* W1    = (const float*)d_in[4];
  const float* b1    = (const float*)d_in[5];
  const float* W2    = (const float*)d_in[6];
  const float* b2    = (const float*)d_in[7];
  float* out = (float*)d_out;

  // workspace layout (all 256B aligned)
  char* base = (char*)d_ws;
  size_t off = 0;
  auto alloc = [&](size_t bytes) -> char* {
    char* p = base + off;
    off += (bytes + 255) & ~(size_t)255;
    return p;
  };
  float* bufA    = (float*)alloc((size_t)N_NODES * IN_FEATS * 4); // h, then h2
  float* bufB    = (float*)alloc((size_t)N_NODES * N_HIDDEN * 4); // hw_scaled
  float* hw2     = (float*)alloc((size_t)N_NODES * N_CLASSES * 4);
  int*   deg_out = (int*)alloc((size_t)3 * N_NODES * 4);          // deg_out|deg_in|cursor
  int*   deg_in  = deg_out + N_NODES;
  int*   cursor  = deg_in + N_NODES;
  float* norm_s  = (float*)alloc((size_t)N_NODES * 4);
  float* norm_d  = (float*)alloc((size_t)N_NODES * 4);
  int*   offs    = (int*)alloc((size_t)(N_NODES + 1) * 4);
  int*   csums   = (int*)alloc((size_t)N_CHUNKS * 4);
  int*   csr_src = (int*)alloc((size_t)N_EDGES * 4);

  hipMemsetAsync(deg_out, 0, (size_t)3 * N_NODES * 4, stream);

  int eb = (N_EDGES + 255) / 256;            // 3125
  int nb = (N_NODES + 255) / 256;            // 196
  k_degree<<<eb, 256, 0, stream>>>(src, dst, deg_out, deg_in);
  k_norm<<<nb, 256, 0, stream>>>(deg_out, deg_in, norm_s, norm_d);
  k_chunksum<<<N_CHUNKS, SCAN_CHUNK, 0, stream>>>(deg_in, csums);
  k_topscan<<<1, 64, 0, stream>>>(csums);
  k_chunkscan<<<N_CHUNKS, SCAN_CHUNK, 0, stream>>>(deg_in, csums, offs);
  k_csr_fill<<<eb, 256, 0, stream>>>(src, dst, offs, cursor, csr_src);

  k_embed<<<N_NODES, 128, 0, stream>>>(feats, emb, bufA);
  k_gemm1<<<N_NODES / 16, 256, 0, stream>>>(bufA, W1, norm_s, bufB);
  k_agg1<<<N_NODES, 256, 0, stream>>>(bufB, offs, csr_src, norm_d, b1, bufA);
  k_gemm2<<<(N_NODES + 31) / 32, 256, 0, stream>>>(bufA, W2, norm_s, hw2);
  k_agg2<<<(N_NODES + 3) / 4, 256, 0, stream>>>(hw2, offs, csr_src, norm_d, b2, out);
}

// Round 2
// 500.301 us; speedup vs baseline: 1.3575x; 1.3575x over previous
//
#include <hip/hip_runtime.h>
#include <math.h>

#define N_NODES 50000
#define SEQ_LEN 32
#define EMB_DIM 128
#define IN_FEATS 256
#define N_HIDDEN 256
#define N_CLASSES 40
#define N_EDGES 800000
#define N_TOKENS 100000

constexpr int SCAN_CHUNK = 512;
constexpr int N_CHUNKS = (N_NODES + SCAN_CHUNK - 1) / SCAN_CHUNK; // 98

__device__ __forceinline__ unsigned short f2bf(float x) {
  unsigned int u = __float_as_uint(x);
  unsigned int r = (u + 0x7FFFu + ((u >> 16) & 1u)) >> 16; // RTNE
  return (unsigned short)r;
}
__device__ __forceinline__ float bf2f(unsigned short s) {
  return __uint_as_float((unsigned int)s << 16);
}

// ---------------- degree / norms ----------------
__global__ __launch_bounds__(256) void k_degree(const int* __restrict__ src,
                                                const int* __restrict__ dst,
                                                int* __restrict__ deg_out,
                                                int* __restrict__ deg_in) {
  int e = blockIdx.x * 256 + threadIdx.x;
  if (e < N_EDGES) {
    atomicAdd(&deg_out[src[e]], 1);
    atomicAdd(&deg_in[dst[e]], 1);
  }
}

__global__ __launch_bounds__(256) void k_norm(const int* __restrict__ deg_out,
                                              const int* __restrict__ deg_in,
                                              float* __restrict__ norm_s,
                                              float* __restrict__ norm_d) {
  int i = blockIdx.x * 256 + threadIdx.x;
  if (i < N_NODES) {
    norm_s[i] = 1.0f / sqrtf((float)max(deg_out[i], 1));
    norm_d[i] = 1.0f / sqrtf((float)max(deg_in[i], 1));
  }
}

// ---------------- scan (offsets from deg_in) ----------------
__global__ __launch_bounds__(SCAN_CHUNK) void k_chunksum(const int* __restrict__ deg,
                                                         int* __restrict__ sums) {
  __shared__ int s[SCAN_CHUNK];
  int i = blockIdx.x * SCAN_CHUNK + threadIdx.x;
  s[threadIdx.x] = (i < N_NODES) ? deg[i] : 0;
  __syncthreads();
  for (int st = SCAN_CHUNK / 2; st > 0; st >>= 1) {
    if (threadIdx.x < st) s[threadIdx.x] += s[threadIdx.x + st];
    __syncthreads();
  }
  if (threadIdx.x == 0) sums[blockIdx.x] = s[0];
}

__global__ void k_topscan(int* __restrict__ sums) {
  if (threadIdx.x == 0 && blockIdx.x == 0) {
    int run = 0;
    for (int b = 0; b < N_CHUNKS; ++b) { int t = sums[b]; sums[b] = run; run += t; }
  }
}

__global__ __launch_bounds__(SCAN_CHUNK) void k_chunkscan(const int* __restrict__ deg,
                                                          const int* __restrict__ chunkOff,
                                                          int* __restrict__ offs) {
  __shared__ int s[SCAN_CHUNK];
  int i = blockIdx.x * SCAN_CHUNK + threadIdx.x;
  int v = (i < N_NODES) ? deg[i] : 0;
  s[threadIdx.x] = v;
  __syncthreads();
  for (int st = 1; st < SCAN_CHUNK; st <<= 1) {
    int t = (threadIdx.x >= st) ? s[threadIdx.x - st] : 0;
    __syncthreads();
    s[threadIdx.x] += t;
    __syncthreads();
  }
  if (i < N_NODES) offs[i + 1] = chunkOff[blockIdx.x] + s[threadIdx.x];
  if (i == 0) offs[0] = 0;
}

__global__ __launch_bounds__(256) void k_csr_fill(const int* __restrict__ src,
                                                  const int* __restrict__ dst,
                                                  const int* __restrict__ offs,
                                                  int* __restrict__ cursor,
                                                  int* __restrict__ csr_src) {
  int e = blockIdx.x * 256 + threadIdx.x;
  if (e < N_EDGES) {
    int d = dst[e];
    int p = atomicAdd(&cursor[d], 1);
    csr_src[offs[d] + p] = src[e];
  }
}

// ---------------- emb table fp32 -> bf16 ----------------
__global__ __launch_bounds__(256) void k_emb2bf(const float* __restrict__ emb,
                                                unsigned short* __restrict__ emb_b) {
  const int total = N_TOKENS * EMB_DIM / 4; // 3.2M float4 groups
  for (int i = blockIdx.x * 256 + threadIdx.x; i < total; i += gridDim.x * 256) {
    float4 v = ((const float4*)emb)[i];
    ushort4 o;
    o.x = f2bf(v.x); o.y = f2bf(v.y); o.z = f2bf(v.z); o.w = f2bf(v.w);
    ((ushort4*)emb_b)[i] = o;
  }
}

// ---------------- embedding + pooling (bf16 gather) ----------------
// 256 threads = 4 nodes x 64 lanes; each lane handles dims (2*lane, 2*lane+1).
__global__ __launch_bounds__(256) void k_embed(const int* __restrict__ feats,
                                               const unsigned short* __restrict__ emb_b,
                                               float* __restrict__ h) {
  int tid = threadIdx.x;
  int lane = tid & 63, sub = tid >> 6;
  int node = blockIdx.x * 4 + sub;
  __shared__ int s_tok[4][SEQ_LEN];
  int tok0 = 0;
  if (lane < SEQ_LEN) {
    tok0 = feats[(size_t)node * SEQ_LEN + lane];
    s_tok[sub][lane] = tok0;
  }
  unsigned long long m = __ballot(lane < SEQ_LEN && tok0 != 0);
  float inv = 1.0f / (float)max(__popcll(m), 1);
  __syncthreads();

  float s0 = 0.f, s1 = 0.f, m0 = -INFINITY, m1 = -INFINITY;
  const unsigned int* rows = (const unsigned int*)emb_b; // 2 bf16 per uint
  #pragma unroll
  for (int t = 0; t < SEQ_LEN; ++t) {
    int tok = s_tok[sub][t];
    unsigned int v = tok ? rows[(size_t)tok * (EMB_DIM / 2) + lane] : 0u;
    float f0 = bf2f((unsigned short)(v & 0xFFFF));
    float f1 = bf2f((unsigned short)(v >> 16));
    s0 += f0; s1 += f1;
    m0 = fmaxf(m0, f0); m1 = fmaxf(m1, f1);
  }
  float2* hv = (float2*)(h + (size_t)node * IN_FEATS);
  hv[lane] = make_float2(s0 * inv, s1 * inv);
  hv[EMB_DIM / 2 + lane] = make_float2(m0, m1);
}

// ---------------- GEMM1: msg = bf16((h @ W1) * norm_s) ----------------
__global__ __launch_bounds__(256) void k_gemm1(const float* __restrict__ h,
                                               const float* __restrict__ W,
                                               const float* __restrict__ norm_s,
                                               unsigned short* __restrict__ out) {
  __shared__ float s_h[16][IN_FEATS]; // 16KB
  int tid = threadIdx.x;
  int r0 = blockIdx.x * 16;
  const float4* hv = (const float4*)(h + (size_t)r0 * IN_FEATS);
  float4* sv = (float4*)s_h;
  #pragma unroll
  for (int idx = tid; idx < 16 * (IN_FEATS / 4); idx += 256) sv[idx] = hv[idx];
  __syncthreads();

  int tx = tid & 63;   // cols 4*tx..4*tx+3
  int ty = tid >> 6;   // rows 4*ty..4*ty+3 (wave-uniform)
  float acc[4][4] = {{0.f}};
  for (int k = 0; k < IN_FEATS; k += 4) {
    float4 a[4];
    #pragma unroll
    for (int r = 0; r < 4; ++r) a[r] = *(const float4*)&s_h[4 * ty + r][k];
    #pragma unroll
    for (int kk = 0; kk < 4; ++kk) {
      float4 w = *(const float4*)(W + (size_t)(k + kk) * N_HIDDEN + 4 * tx);
      #pragma unroll
      for (int r = 0; r < 4; ++r) {
        float av = (kk == 0) ? a[r].x : (kk == 1) ? a[r].y : (kk == 2) ? a[r].z : a[r].w;
        acc[r][0] += av * w.x;
        acc[r][1] += av * w.y;
        acc[r][2] += av * w.z;
        acc[r][3] += av * w.w;
      }
    }
  }
  #pragma unroll
  for (int r = 0; r < 4; ++r) {
    int row = r0 + 4 * ty + r;
    float ns = norm_s[row];
    ushort4 o;
    o.x = f2bf(acc[r][0] * ns);
    o.y = f2bf(acc[r][1] * ns);
    o.z = f2bf(acc[r][2] * ns);
    o.w = f2bf(acc[r][3] * ns);
    *(ushort4*)(out + (size_t)row * N_HIDDEN + 4 * tx) = o;
  }
}

// ---------------- aggregation layer 1 (bf16 msgs, relu+bias+norm_d) ----------------
// 256 threads = 2 nodes x 128 lanes; lane handles features (2t, 2t+1).
__global__ __launch_bounds__(256) void k_agg1(const unsigned short* __restrict__ msgb,
                                              const int* __restrict__ offs,
                                              const int* __restrict__ csr_src,
                                              const float* __restrict__ norm_d,
                                              const float* __restrict__ b1,
                                              float* __restrict__ out) {
  int tid = threadIdx.x;
  int t = tid & 127, sub = tid >> 7;
  int node = blockIdx.x * 2 + sub;
  int beg = offs[node], end = offs[node + 1];
  const unsigned int* rows = (const unsigned int*)msgb; // row stride 128 uints
  float a0 = 0.f, a1 = 0.f;

  int e = beg;
  for (; e + 4 <= end; e += 4) {
    int s0 = csr_src[e], s1 = csr_src[e + 1], s2 = csr_src[e + 2], s3 = csr_src[e + 3];
    unsigned int v0 = rows[(size_t)s0 * 128 + t];
    unsigned int v1 = rows[(size_t)s1 * 128 + t];
    unsigned int v2 = rows[(size_t)s2 * 128 + t];
    unsigned int v3 = rows[(size_t)s3 * 128 + t];
    a0 += bf2f((unsigned short)(v0 & 0xFFFF)); a1 += bf2f((unsigned short)(v0 >> 16));
    a0 += bf2f((unsigned short)(v1 & 0xFFFF)); a1 += bf2f((unsigned short)(v1 >> 16));
    a0 += bf2f((unsigned short)(v2 & 0xFFFF)); a1 += bf2f((unsigned short)(v2 >> 16));
    a0 += bf2f((unsigned short)(v3 & 0xFFFF)); a1 += bf2f((unsigned short)(v3 >> 16));
  }
  for (; e < end; ++e) {
    int s = csr_src[e];
    unsigned int v = rows[(size_t)s * 128 + t];
    a0 += bf2f((unsigned short)(v & 0xFFFF));
    a1 += bf2f((unsigned short)(v >> 16));
  }
  float nd = norm_d[node];
  float o0 = fmaxf(a0 * nd + b1[2 * t], 0.f);
  float o1 = fmaxf(a1 * nd + b1[2 * t + 1], 0.f);
  ((float2*)(out + (size_t)node * N_HIDDEN))[t] = make_float2(o0, o1);
}

// ---------------- GEMM2: hw2 = (h2 @ W2) * norm_s ----------------
__global__ __launch_bounds__(256) void k_gemm2(const float* __restrict__ h2,
                                               const float* __restrict__ W2,
                                               const float* __restrict__ norm_s,
                                               float* __restrict__ out) {
  __shared__ float s_h[32][N_HIDDEN + 1];
  int tid = threadIdx.x;
  int r0 = blockIdx.x * 32;
  for (int idx = tid; idx < 32 * N_HIDDEN; idx += 256) {
    int r = idx >> 8, k = idx & 255;
    int row = r0 + r;
    s_h[r][k] = (row < N_NODES) ? h2[(size_t)row * N_HIDDEN + k] : 0.f;
  }
  __syncthreads();

  float acc[5] = {0.f, 0.f, 0.f, 0.f, 0.f};
  int rr[5], jj[5];
  #pragma unroll
  for (int i = 0; i < 5; ++i) {
    int o = tid + i * 256;
    rr[i] = o & 31;
    jj[i] = o >> 5;
  }
  for (int k = 0; k < N_HIDDEN; ++k) {
    #pragma unroll
    for (int i = 0; i < 5; ++i) acc[i] += s_h[rr[i]][k] * W2[(size_t)k * N_CLASSES + jj[i]];
  }
  #pragma unroll
  for (int i = 0; i < 5; ++i) {
    int row = r0 + rr[i];
    if (row < N_NODES) out[(size_t)row * N_CLASSES + jj[i]] = acc[i] * norm_s[row];
  }
}

// ---------------- aggregation layer 2 (bias + norm_d) -> d_out ----------------
__global__ __launch_bounds__(256) void k_agg2(const float* __restrict__ msg,
                                              const int* __restrict__ offs,
                                              const int* __restrict__ csr_src,
                                              const float* __restrict__ norm_d,
                                              const float* __restrict__ b2,
                                              float* __restrict__ out) {
  int tid = threadIdx.x;
  int lane = tid & 63, sub = tid >> 6;
  int node = blockIdx.x * 4 + sub;
  if (node >= N_NODES) return;
  int beg = offs[node], end = offs[node + 1];
  if (lane < N_CLASSES) {
    float acc = 0.f;
    int e = beg;
    for (; e + 4 <= end; e += 4) {
      int s0 = csr_src[e], s1 = csr_src[e + 1], s2 = csr_src[e + 2], s3 = csr_src[e + 3];
      float v0 = msg[(size_t)s0 * N_CLASSES + lane];
      float v1 = msg[(size_t)s1 * N_CLASSES + lane];
      float v2 = msg[(size_t)s2 * N_CLASSES + lane];
      float v3 = msg[(size_t)s3 * N_CLASSES + lane];
      acc += v0 + v1 + v2 + v3;
    }
    for (; e < end; ++e) acc += msg[(size_t)csr_src[e] * N_CLASSES + lane];
    out[(size_t)node * N_CLASSES + lane] = acc * norm_d[node] + b2[lane];
  }
}

extern "C" void kernel_launch(void* const* d_in, const int* in_sizes, int n_in,
                              void* d_out, int out_size, void* d_ws, size_t ws_size,
                              hipStream_t stream) {
  const int*   feats = (const int*)d_in[0];
  const int*   src   = (const int*)d_in[1];
  const int*   dst   = (const int*)d_in[2];
  const float* emb   = (const float*)d_in[3];
  const float* W1    = (const float*)d_in[4];
  const float* b1    = (const float*)d_in[5];
  const float* W2    = (const float*)d_in[6];
  const float* b2    = (const float*)d_in[7];
  float* out = (float*)d_out;

  char* base = (char*)d_ws;
  size_t off = 0;
  auto alloc = [&](size_t bytes) -> char* {
    char* p = base + off;
    off += (bytes + 255) & ~(size_t)255;
    return p;
  };
  float*          bufA    = (float*)alloc((size_t)N_NODES * IN_FEATS * 4);   // h, then h2
  unsigned short* msgb    = (unsigned short*)alloc((size_t)N_NODES * N_HIDDEN * 2); // bf16 msgs
  float*          hw2     = (float*)alloc((size_t)N_NODES * N_CLASSES * 4);
  unsigned short* emb_b   = (unsigned short*)alloc((size_t)N_TOKENS * EMB_DIM * 2);
  int*   deg_out = (int*)alloc((size_t)3 * N_NODES * 4);
  int*   deg_in  = deg_out + N_NODES;
  int*   cursor  = deg_in + N_NODES;
  float* norm_s  = (float*)alloc((size_t)N_NODES * 4);
  float* norm_d  = (float*)alloc((size_t)N_NODES * 4);
  int*   offs    = (int*)alloc((size_t)(N_NODES + 1) * 4);
  int*   csums   = (int*)alloc((size_t)N_CHUNKS * 4);
  int*   csr_src = (int*)alloc((size_t)N_EDGES * 4);

  hipMemsetAsync(deg_out, 0, (size_t)3 * N_NODES * 4, stream);

  int eb = (N_EDGES + 255) / 256;
  int nb = (N_NODES + 255) / 256;
  k_emb2bf<<<2048, 256, 0, stream>>>(emb, emb_b);
  k_degree<<<eb, 256, 0, stream>>>(src, dst, deg_out, deg_in);
  k_norm<<<nb, 256, 0, stream>>>(deg_out, deg_in, norm_s, norm_d);
  k_chunksum<<<N_CHUNKS, SCAN_CHUNK, 0, stream>>>(deg_in, csums);
  k_topscan<<<1, 64, 0, stream>>>(csums);
  k_chunkscan<<<N_CHUNKS, SCAN_CHUNK, 0, stream>>>(deg_in, csums, offs);
  k_csr_fill<<<eb, 256, 0, stream>>>(src, dst, offs, cursor, csr_src);

  k_embed<<<N_NODES / 4, 256, 0, stream>>>(feats, emb_b, bufA);
  k_gemm1<<<N_NODES / 16, 256, 0, stream>>>(bufA, W1, norm_s, msgb);
  k_agg1<<<N_NODES / 2, 256, 0, stream>>>(msgb, offs, csr_src, norm_d, b1, bufA);
  k_gemm2<<<(N_NODES + 31) / 32, 256, 0, stream>>>(bufA, W2, norm_s, hw2);
  k_agg2<<<(N_NODES + 3) / 4, 256, 0, stream>>>(hw2, offs, csr_src, norm_d, b2, out);
}

// Round 3
// 323.824 us; speedup vs baseline: 2.0973x; 1.5450x over previous
//
#include <hip/hip_runtime.h>
#include <math.h>

#define N_NODES 50000
#define SEQ_LEN 32
#define EMB_DIM 128
#define IN_FEATS 256
#define N_HIDDEN 256
#define N_CLASSES 40
#define N_EDGES 800000
#define N_TOKENS 100000

constexpr int SCAN_CHUNK = 512;
constexpr int N_CHUNKS = (N_NODES + SCAN_CHUNK - 1) / SCAN_CHUNK; // 98

typedef short short8 __attribute__((ext_vector_type(8)));
typedef float f32x4 __attribute__((ext_vector_type(4)));

__device__ __forceinline__ unsigned short f2bf(float x) {
  unsigned int u = __float_as_uint(x);
  unsigned int r = (u + 0x7FFFu + ((u >> 16) & 1u)) >> 16; // RTNE
  return (unsigned short)r;
}
__device__ __forceinline__ float bf2f(unsigned short s) {
  return __uint_as_float((unsigned int)s << 16);
}
__device__ __forceinline__ unsigned int pack2bf(float a, float b) {
  return (unsigned int)f2bf(a) | ((unsigned int)f2bf(b) << 16);
}

// ---------------- degree / norms ----------------
__global__ __launch_bounds__(256) void k_degree(const int* __restrict__ src,
                                                const int* __restrict__ dst,
                                                int* __restrict__ deg_out,
                                                int* __restrict__ deg_in) {
  int e = blockIdx.x * 256 + threadIdx.x;
  if (e < N_EDGES) {
    atomicAdd(&deg_out[src[e]], 1);
    atomicAdd(&deg_in[dst[e]], 1);
  }
}

__global__ __launch_bounds__(256) void k_norm(const int* __restrict__ deg_out,
                                              const int* __restrict__ deg_in,
                                              float* __restrict__ norm_s,
                                              float* __restrict__ norm_d) {
  int i = blockIdx.x * 256 + threadIdx.x;
  if (i < N_NODES) {
    norm_s[i] = 1.0f / sqrtf((float)max(deg_out[i], 1));
    norm_d[i] = 1.0f / sqrtf((float)max(deg_in[i], 1));
  }
}

// ---------------- scan ----------------
__global__ __launch_bounds__(SCAN_CHUNK) void k_chunksum(const int* __restrict__ deg,
                                                         int* __restrict__ sums) {
  __shared__ int s[SCAN_CHUNK];
  int i = blockIdx.x * SCAN_CHUNK + threadIdx.x;
  s[threadIdx.x] = (i < N_NODES) ? deg[i] : 0;
  __syncthreads();
  for (int st = SCAN_CHUNK / 2; st > 0; st >>= 1) {
    if (threadIdx.x < st) s[threadIdx.x] += s[threadIdx.x + st];
    __syncthreads();
  }
  if (threadIdx.x == 0) sums[blockIdx.x] = s[0];
}

__global__ void k_topscan(int* __restrict__ sums) {
  if (threadIdx.x == 0 && blockIdx.x == 0) {
    int run = 0;
    for (int b = 0; b < N_CHUNKS; ++b) { int t = sums[b]; sums[b] = run; run += t; }
  }
}

__global__ __launch_bounds__(SCAN_CHUNK) void k_chunkscan(const int* __restrict__ deg,
                                                          const int* __restrict__ chunkOff,
                                                          int* __restrict__ offs) {
  __shared__ int s[SCAN_CHUNK];
  int i = blockIdx.x * SCAN_CHUNK + threadIdx.x;
  int v = (i < N_NODES) ? deg[i] : 0;
  s[threadIdx.x] = v;
  __syncthreads();
  for (int st = 1; st < SCAN_CHUNK; st <<= 1) {
    int t = (threadIdx.x >= st) ? s[threadIdx.x - st] : 0;
    __syncthreads();
    s[threadIdx.x] += t;
    __syncthreads();
  }
  if (i < N_NODES) offs[i + 1] = chunkOff[blockIdx.x] + s[threadIdx.x];
  if (i == 0) offs[0] = 0;
}

__global__ __launch_bounds__(256) void k_csr_fill(const int* __restrict__ src,
                                                  const int* __restrict__ dst,
                                                  const int* __restrict__ offs,
                                                  int* __restrict__ cursor,
                                                  int* __restrict__ csr_src) {
  int e = blockIdx.x * 256 + threadIdx.x;
  if (e < N_EDGES) {
    int d = dst[e];
    int p = atomicAdd(&cursor[d], 1);
    csr_src[offs[d] + p] = src[e];
  }
}

// ---------------- emb table fp32 -> bf16 ----------------
__global__ __launch_bounds__(256) void k_emb2bf(const float* __restrict__ emb,
                                                unsigned short* __restrict__ emb_b) {
  const int total = N_TOKENS * EMB_DIM / 4;
  for (int i = blockIdx.x * 256 + threadIdx.x; i < total; i += gridDim.x * 256) {
    float4 v = ((const float4*)emb)[i];
    ushort4 o;
    o.x = f2bf(v.x); o.y = f2bf(v.y); o.z = f2bf(v.z); o.w = f2bf(v.w);
    ((ushort4*)emb_b)[i] = o;
  }
}

// ---------------- W1 pack: fragment-major bf16 ----------------
// Wp1[((kt*16 + jb)*64 + lane)] = 8 bf16: W[kt*32 + (lane>>4)*8 + e][jb*16 + (lane&15)]
__global__ __launch_bounds__(256) void k_packW1(const float* __restrict__ W,
                                                unsigned short* __restrict__ Wp) {
  int g = blockIdx.x * 256 + threadIdx.x; // 8192 total
  int lane = g & 63, jb = (g >> 6) & 15, kt = g >> 10;
  int col = jb * 16 + (lane & 15);
  int kbase = kt * 32 + (lane >> 4) * 8;
  ushort4 lo, hi;
  unsigned short v[8];
  #pragma unroll
  for (int e = 0; e < 8; ++e) v[e] = f2bf(W[(size_t)(kbase + e) * N_HIDDEN + col]);
  unsigned short* o = Wp + (size_t)g * 8;
  #pragma unroll
  for (int e = 0; e < 8; ++e) o[e] = v[e];
}

// Wp2: 8 kt x 3 jb x 64 lanes, cols >= 40 zero-padded
__global__ __launch_bounds__(256) void k_packW2(const float* __restrict__ W,
                                                unsigned short* __restrict__ Wp) {
  int g = blockIdx.x * 256 + threadIdx.x; // 1536 total
  if (g >= 8 * 3 * 64) return;
  int lane = g & 63, jb = (g >> 6) % 3, kt = g / (3 * 64);
  int col = jb * 16 + (lane & 15);
  int kbase = kt * 32 + (lane >> 4) * 8;
  unsigned short* o = Wp + (size_t)g * 8;
  #pragma unroll
  for (int e = 0; e < 8; ++e)
    o[e] = (col < N_CLASSES) ? f2bf(W[(size_t)(kbase + e) * N_CLASSES + col]) : (unsigned short)0;
}

// ---------------- embedding + pooling (bf16 gather, bf16 h out) ----------------
__global__ __launch_bounds__(256) void k_embed(const int* __restrict__ feats,
                                               const unsigned short* __restrict__ emb_b,
                                               unsigned int* __restrict__ h) { // h as uint pairs
  int tid = threadIdx.x;
  int lane = tid & 63, sub = tid >> 6;
  int node = blockIdx.x * 4 + sub;
  __shared__ int s_tok[4][SEQ_LEN];
  int tok0 = 0;
  if (lane < SEQ_LEN) {
    tok0 = feats[(size_t)node * SEQ_LEN + lane];
    s_tok[sub][lane] = tok0;
  }
  unsigned long long m = __ballot(lane < SEQ_LEN && tok0 != 0);
  float inv = 1.0f / (float)max(__popcll(m), 1);
  __syncthreads();

  float s0 = 0.f, s1 = 0.f, m0 = -INFINITY, m1 = -INFINITY;
  const unsigned int* rows = (const unsigned int*)emb_b;
  #pragma unroll
  for (int t = 0; t < SEQ_LEN; ++t) {
    int tok = s_tok[sub][t];
    unsigned int v = tok ? rows[(size_t)tok * (EMB_DIM / 2) + lane] : 0u;
    float f0 = bf2f((unsigned short)(v & 0xFFFF));
    float f1 = bf2f((unsigned short)(v >> 16));
    s0 += f0; s1 += f1;
    m0 = fmaxf(m0, f0); m1 = fmaxf(m1, f1);
  }
  unsigned int* hv = h + (size_t)node * (IN_FEATS / 2);
  hv[lane] = pack2bf(s0 * inv, s1 * inv);
  hv[EMB_DIM / 2 + lane] = pack2bf(m0, m1);
}

// ---------------- MFMA GEMM1: msgb = bf16((h @ W1) * norm_s) ----------------
// 64 rows x 256 cols per block; 4 waves, wave w -> cols 64w..64w+63.
__global__ __launch_bounds__(256) void k_mm1(const unsigned short* __restrict__ hb,
                                             const unsigned short* __restrict__ Wp,
                                             const float* __restrict__ norm_s,
                                             unsigned short* __restrict__ out) {
  __shared__ unsigned short sA[64 * 256]; // 32KB, XOR-swizzled 16B granules
  int tid = threadIdx.x;
  int r0 = blockIdx.x * 64;
  // stage: 64 rows x 32 granules of 16B
  #pragma unroll
  for (int it = 0; it < 8; ++it) {
    int idx = it * 256 + tid;
    int r = idx >> 5, kb = idx & 31;
    uint4 v = make_uint4(0, 0, 0, 0);
    int row = r0 + r;
    if (row < N_NODES) v = *(const uint4*)(hb + (size_t)row * 256 + kb * 8);
    *(uint4*)&sA[r * 256 + ((kb ^ (r & 7)) << 3)] = v;
  }
  __syncthreads();

  int w = tid >> 6, lane = tid & 63;
  const short8* W8 = (const short8*)Wp;
  f32x4 acc[4][4];
  #pragma unroll
  for (int i = 0; i < 4; ++i)
    #pragma unroll
    for (int j = 0; j < 4; ++j) acc[i][j] = (f32x4){0.f, 0.f, 0.f, 0.f};

  #pragma unroll
  for (int kt = 0; kt < 8; ++kt) {
    short8 a[4], b[4];
    int kb = kt * 4 + (lane >> 4);
    #pragma unroll
    for (int ri = 0; ri < 4; ++ri) {
      int r = ri * 16 + (lane & 15);
      a[ri] = *(const short8*)&sA[r * 256 + ((kb ^ (r & 7)) << 3)];
    }
    #pragma unroll
    for (int jb = 0; jb < 4; ++jb) b[jb] = W8[(kt * 16 + w * 4 + jb) * 64 + lane];
    #pragma unroll
    for (int ri = 0; ri < 4; ++ri)
      #pragma unroll
      for (int jb = 0; jb < 4; ++jb)
        acc[ri][jb] = __builtin_amdgcn_mfma_f32_16x16x32_bf16(a[ri], b[jb], acc[ri][jb], 0, 0, 0);
  }

  #pragma unroll
  for (int ri = 0; ri < 4; ++ri) {
    #pragma unroll
    for (int rr = 0; rr < 4; ++rr) {
      int row = r0 + ri * 16 + (lane >> 4) * 4 + rr;
      if (row < N_NODES) {
        float ns = norm_s[row];
        #pragma unroll
        for (int jb = 0; jb < 4; ++jb) {
          int col = w * 64 + jb * 16 + (lane & 15);
          out[(size_t)row * 256 + col] = f2bf(acc[ri][jb][rr] * ns);
        }
      }
    }
  }
}

// ---------------- aggregation layer 1 (bf16 msgs, relu+bias+norm_d, bf16 out) ----------------
__global__ __launch_bounds__(256) void k_agg1(const unsigned short* __restrict__ msgb,
                                              const int* __restrict__ offs,
                                              const int* __restrict__ csr_src,
                                              const float* __restrict__ norm_d,
                                              const float* __restrict__ b1,
                                              unsigned int* __restrict__ out) {
  int tid = threadIdx.x;
  int t = tid & 127, sub = tid >> 7;
  int node = blockIdx.x * 2 + sub;
  int beg = offs[node], end = offs[node + 1];
  const unsigned int* rows = (const unsigned int*)msgb;
  float a0 = 0.f, a1 = 0.f;

  int e = beg;
  for (; e + 4 <= end; e += 4) {
    int s0 = csr_src[e], s1 = csr_src[e + 1], s2 = csr_src[e + 2], s3 = csr_src[e + 3];
    unsigned int v0 = rows[(size_t)s0 * 128 + t];
    unsigned int v1 = rows[(size_t)s1 * 128 + t];
    unsigned int v2 = rows[(size_t)s2 * 128 + t];
    unsigned int v3 = rows[(size_t)s3 * 128 + t];
    a0 += bf2f((unsigned short)(v0 & 0xFFFF)); a1 += bf2f((unsigned short)(v0 >> 16));
    a0 += bf2f((unsigned short)(v1 & 0xFFFF)); a1 += bf2f((unsigned short)(v1 >> 16));
    a0 += bf2f((unsigned short)(v2 & 0xFFFF)); a1 += bf2f((unsigned short)(v2 >> 16));
    a0 += bf2f((unsigned short)(v3 & 0xFFFF)); a1 += bf2f((unsigned short)(v3 >> 16));
  }
  for (; e < end; ++e) {
    int s = csr_src[e];
    unsigned int v = rows[(size_t)s * 128 + t];
    a0 += bf2f((unsigned short)(v & 0xFFFF));
    a1 += bf2f((unsigned short)(v >> 16));
  }
  float nd = norm_d[node];
  float o0 = fmaxf(a0 * nd + b1[2 * t], 0.f);
  float o1 = fmaxf(a1 * nd + b1[2 * t + 1], 0.f);
  out[(size_t)node * 128 + t] = pack2bf(o0, o1);
}

// ---------------- MFMA GEMM2: hw2b = bf16((h2 @ W2) * norm_s), N padded 40->48 ----------------
// 64 rows x 48 cols per block; wave w -> rows 16w..16w+15.
__global__ __launch_bounds__(256) void k_mm2(const unsigned short* __restrict__ h2b,
                                             const unsigned short* __restrict__ Wp,
                                             const float* __restrict__ norm_s,
                                             unsigned short* __restrict__ out) {
  __shared__ unsigned short sA[64 * 256];
  int tid = threadIdx.x;
  int r0 = blockIdx.x * 64;
  #pragma unroll
  for (int it = 0; it < 8; ++it) {
    int idx = it * 256 + tid;
    int r = idx >> 5, kb = idx & 31;
    uint4 v = make_uint4(0, 0, 0, 0);
    int row = r0 + r;
    if (row < N_NODES) v = *(const uint4*)(h2b + (size_t)row * 256 + kb * 8);
    *(uint4*)&sA[r * 256 + ((kb ^ (r & 7)) << 3)] = v;
  }
  __syncthreads();

  int w = tid >> 6, lane = tid & 63;
  const short8* W8 = (const short8*)Wp;
  f32x4 acc[3];
  #pragma unroll
  for (int j = 0; j < 3; ++j) acc[j] = (f32x4){0.f, 0.f, 0.f, 0.f};

  #pragma unroll
  for (int kt = 0; kt < 8; ++kt) {
    int r = w * 16 + (lane & 15);
    int kb = kt * 4 + (lane >> 4);
    short8 a = *(const short8*)&sA[r * 256 + ((kb ^ (r & 7)) << 3)];
    #pragma unroll
    for (int jb = 0; jb < 3; ++jb) {
      short8 b = W8[(kt * 3 + jb) * 64 + lane];
      acc[jb] = __builtin_amdgcn_mfma_f32_16x16x32_bf16(a, b, acc[jb], 0, 0, 0);
    }
  }

  #pragma unroll
  for (int rr = 0; rr < 4; ++rr) {
    int row = r0 + w * 16 + (lane >> 4) * 4 + rr;
    if (row < N_NODES) {
      float ns = norm_s[row];
      #pragma unroll
      for (int jb = 0; jb < 3; ++jb) {
        int col = jb * 16 + (lane & 15);
        if (col < N_CLASSES) out[(size_t)row * N_CLASSES + col] = f2bf(acc[jb][rr] * ns);
      }
    }
  }
}

// ---------------- aggregation layer 2 (bf16 msgs, bias + norm_d) -> fp32 d_out ----------------
__global__ __launch_bounds__(256) void k_agg2(const unsigned short* __restrict__ msgb,
                                              const int* __restrict__ offs,
                                              const int* __restrict__ csr_src,
                                              const float* __restrict__ norm_d,
                                              const float* __restrict__ b2,
                                              float* __restrict__ out) {
  int tid = threadIdx.x;
  int lane = tid & 63, sub = tid >> 6;
  int node = blockIdx.x * 4 + sub;
  if (node >= N_NODES) return;
  int beg = offs[node], end = offs[node + 1];
  if (lane < N_CLASSES) {
    float acc = 0.f;
    int e = beg;
    for (; e + 4 <= end; e += 4) {
      int s0 = csr_src[e], s1 = csr_src[e + 1], s2 = csr_src[e + 2], s3 = csr_src[e + 3];
      float v0 = bf2f(msgb[(size_t)s0 * N_CLASSES + lane]);
      float v1 = bf2f(msgb[(size_t)s1 * N_CLASSES + lane]);
      float v2 = bf2f(msgb[(size_t)s2 * N_CLASSES + lane]);
      float v3 = bf2f(msgb[(size_t)s3 * N_CLASSES + lane]);
      acc += v0 + v1 + v2 + v3;
    }
    for (; e < end; ++e) acc += bf2f(msgb[(size_t)csr_src[e] * N_CLASSES + lane]);
    out[(size_t)node * N_CLASSES + lane] = acc * norm_d[node] + b2[lane];
  }
}

extern "C" void kernel_launch(void* const* d_in, const int* in_sizes, int n_in,
                              void* d_out, int out_size, void* d_ws, size_t ws_size,
                              hipStream_t stream) {
  const int*   feats = (const int*)d_in[0];
  const int*   src   = (const int*)d_in[1];
  const int*   dst   = (const int*)d_in[2];
  const float* emb   = (const float*)d_in[3];
  const float* W1    = (const float*)d_in[4];
  const float* b1    = (const float*)d_in[5];
  const float* W2    = (const float*)d_in[6];
  const float* b2    = (const float*)d_in[7];
  float* out = (float*)d_out;

  char* base = (char*)d_ws;
  size_t off = 0;
  auto alloc = [&](size_t bytes) -> char* {
    char* p = base + off;
    off += (bytes + 255) & ~(size_t)255;
    return p;
  };
  unsigned short* hb      = (unsigned short*)alloc((size_t)N_NODES * IN_FEATS * 2);  // h bf16; reused as h2b
  unsigned short* msgb    = (unsigned short*)alloc((size_t)N_NODES * N_HIDDEN * 2);
  unsigned short* hw2b    = (unsigned short*)alloc((size_t)N_NODES * N_CLASSES * 2);
  unsigned short* emb_b   = (unsigned short*)alloc((size_t)N_TOKENS * EMB_DIM * 2);
  unsigned short* Wp1     = (unsigned short*)alloc((size_t)8 * 16 * 64 * 8 * 2);
  unsigned short* Wp2     = (unsigned short*)alloc((size_t)8 * 3 * 64 * 8 * 2);
  int*   deg_out = (int*)alloc((size_t)3 * N_NODES * 4);
  int*   deg_in  = deg_out + N_NODES;
  int*   cursor  = deg_in + N_NODES;
  float* norm_s  = (float*)alloc((size_t)N_NODES * 4);
  float* norm_d  = (float*)alloc((size_t)N_NODES * 4);
  int*   offs    = (int*)alloc((size_t)(N_NODES + 1) * 4);
  int*   csums   = (int*)alloc((size_t)N_CHUNKS * 4);
  int*   csr_src = (int*)alloc((size_t)N_EDGES * 4);

  hipMemsetAsync(deg_out, 0, (size_t)3 * N_NODES * 4, stream);

  int eb = (N_EDGES + 255) / 256;
  int nb = (N_NODES + 255) / 256;
  k_emb2bf<<<2048, 256, 0, stream>>>(emb, emb_b);
  k_packW1<<<32, 256, 0, stream>>>(W1, Wp1);
  k_packW2<<<6, 256, 0, stream>>>(W2, Wp2);
  k_degree<<<eb, 256, 0, stream>>>(src, dst, deg_out, deg_in);
  k_norm<<<nb, 256, 0, stream>>>(deg_out, deg_in, norm_s, norm_d);
  k_chunksum<<<N_CHUNKS, SCAN_CHUNK, 0, stream>>>(deg_in, csums);
  k_topscan<<<1, 64, 0, stream>>>(csums);
  k_chunkscan<<<N_CHUNKS, SCAN_CHUNK, 0, stream>>>(deg_in, csums, offs);
  k_csr_fill<<<eb, 256, 0, stream>>>(src, dst, offs, cursor, csr_src);

  int gemm_blocks = (N_NODES + 63) / 64; // 782
  k_embed<<<N_NODES / 4, 256, 0, stream>>>(feats, emb_b, (unsigned int*)hb);
  k_mm1<<<gemm_blocks, 256, 0, stream>>>(hb, Wp1, norm_s, msgb);
  k_agg1<<<N_NODES / 2, 256, 0, stream>>>(msgb, offs, csr_src, norm_d, b1, (unsigned int*)hb);
  k_mm2<<<gemm_blocks, 256, 0, stream>>>(hb, Wp2, norm_s, hw2b);
  k_agg2<<<(N_NODES + 3) / 4, 256, 0, stream>>>(hw2b, offs, csr_src, norm_d, b2, out);
}